// Round 6
// baseline (328.308 us; speedup 1.0000x reference)
//
#include <hip/hip_runtime.h>

// Problem constants (match reference setup_inputs)
#define BB 16
#define NN 2048
#define EE 32768
#define DD 256
#define RR 8
#define LL 2
#define BUCKETS (RR * NN)   // 16384 buckets per batch
#define TM 64               // GEMM m-tile

typedef unsigned short u16;
typedef __attribute__((__ext_vector_type__(8))) __bf16 bfx8;   // MFMA A/B frag
typedef __attribute__((__ext_vector_type__(16))) float fx16;   // MFMA acc
typedef __attribute__((__ext_vector_type__(2))) float f32x2;   // v_pk_add_f32

__device__ __forceinline__ float blo(unsigned u){ union{unsigned x;float f;}c; c.x=u<<16; return c.f; }
__device__ __forceinline__ float bhi(unsigned u){ union{unsigned x;float f;}c; c.x=u&0xffff0000u; return c.f; }
__device__ __forceinline__ u16 f2bf(float f){ union{float f;unsigned u;}x; x.f=f;
    return (u16)((x.u + 0x7FFFu + ((x.u>>16)&1u))>>16); }           // RNE
__device__ __forceinline__ unsigned pk2(float a, float b){
    return (unsigned)f2bf(a) | ((unsigned)f2bf(b)<<16); }

// ---------------------------------------------------------------------------
// prep0: (a) weight prep into MFMA-B fragment order (144 blocks)
//        Wf[ls][kt(8)][nt8(8)][ks2(2)][fl(64)][e(8)] bf16,
//        n = nt8*32+(fl&31), k = kt*32+ks2*16+(fl>>5)*8+e, val = Wsrc[k][n]
//        (b) zero counts (remaining blocks)
// ---------------------------------------------------------------------------
__global__ __launch_bounds__(256) void prep0(const float* __restrict__ W,
                                             const float* __restrict__ Wroot,
                                             u16* __restrict__ Wf,
                                             int* __restrict__ counts, int bc)
{
    int t = threadIdx.x;
    if (blockIdx.x < 8 * LL * 9) {
        __shared__ float tl[32][257];   // [k][n], padded
        int kt = blockIdx.x & 7, ls = blockIdx.x >> 3;
        int l = ls / 9, seg = ls - l * 9;
        const float* src = (seg < 8) ? W + (size_t)(l * RR + seg) * DD * DD
                                     : Wroot + (size_t)l * DD * DD;
        for (int k8 = 0; k8 < 32; ++k8)
            tl[k8][t] = src[(size_t)(kt * 32 + k8) * DD + t];
        __syncthreads();
        #pragma unroll
        for (int i = 0; i < 4; ++i) {
            int o = i * 256 + t;                 // o = nt8*128 + ks2*64 + fl
            int fl = o & 63, ks2 = (o >> 6) & 1, nt8 = o >> 7;
            int n = nt8 * 32 + (fl & 31);
            int kb = ks2 * 16 + (fl >> 5) * 8;
            unsigned d0 = pk2(tl[kb + 0][n], tl[kb + 1][n]);
            unsigned d1 = pk2(tl[kb + 2][n], tl[kb + 3][n]);
            unsigned d2 = pk2(tl[kb + 4][n], tl[kb + 5][n]);
            unsigned d3 = pk2(tl[kb + 6][n], tl[kb + 7][n]);
            *(uint4*)(Wf + (((size_t)ls * 8 + kt) * 1024 + o) * 8) =
                make_uint4(d0, d1, d2, d3);
        }
    } else {
        int idx = (blockIdx.x - 8 * LL * 9) * 256 + t;   // int4 granules
        int tot = bc * BUCKETS / 4;
        if (idx < tot) ((int4*)counts)[idx] = make_int4(0, 0, 0, 0);
    }
}

// ---------------------------------------------------------------------------
// prep1: (a) gather x0 = bf16(emb[nodes]) (bc*512 blocks)
//        (b) counts[bb][r][dst] += 1 per edge (bc*128 blocks)
// ---------------------------------------------------------------------------
__global__ __launch_bounds__(256) void prep1(const int* __restrict__ nodes,
                                             const float* __restrict__ emb,
                                             u16* __restrict__ x0,
                                             const int* __restrict__ edges,
                                             const int* __restrict__ types,
                                             int* __restrict__ counts,
                                             int b0, int bc)
{
    int ng = bc * 512;
    if ((int)blockIdx.x < ng) {
        int t = blockIdx.x * 256 + threadIdx.x;
        int lane = t & 63;
        int row = t >> 6;
        int bb = row / NN;
        int n  = row - bb * NN;
        int v  = nodes[(size_t)(b0 + bb) * NN + n];
        float4 val = *((const float4*)(emb + (size_t)v * DD) + lane);
        ushort4 o;
        o.x = f2bf(val.x); o.y = f2bf(val.y); o.z = f2bf(val.z); o.w = f2bf(val.w);
        *((ushort4*)(x0 + (size_t)row * DD) + lane) = o;
    } else {
        int t = (blockIdx.x - ng) * 256 + threadIdx.x;
        int bb = t / EE;
        int e  = t - bb * EE;
        const int* eb = edges + (size_t)(b0 + bb) * 2 * EE;
        int dst = eb[EE + e];
        int r   = types[(size_t)(b0 + bb) * EE + e];
        atomicAdd(&counts[((size_t)bb * RR + r) * NN + dst], 1);
    }
}

// ---------------------------------------------------------------------------
// scan2: per-batch exclusive scan of counts (16384 buckets) -> offsets+cursor,
// plus invdeg[bb][n] = 1/max(sum_r counts, 1). One block per batch.
// ---------------------------------------------------------------------------
__global__ __launch_bounds__(256) void scan2_k(const int* __restrict__ counts,
                                               int* __restrict__ offsets,
                                               int* __restrict__ cursor,
                                               float* __restrict__ invdeg)
{
    int bb = blockIdx.x;
    int tid = threadIdx.x;
    size_t base = (size_t)bb * BUCKETS;
    __shared__ int sums[256];

    int tot = 0;
    #pragma unroll 4
    for (int i = 0; i < 64; ++i) tot += counts[base + tid * 64 + i];
    sums[tid] = tot;
    __syncthreads();
    for (int off = 1; off < 256; off <<= 1) {
        int v = (tid >= off) ? sums[tid - off] : 0;
        __syncthreads();
        sums[tid] += v;
        __syncthreads();
    }
    int run = sums[tid] - tot;
    for (int i = 0; i < 64; ++i) {
        size_t idx = base + tid * 64 + i;
        offsets[idx] = run;
        cursor[idx]  = run;
        run += counts[idx];
    }
    // invdeg: thread handles 8 consecutive n
    #pragma unroll
    for (int i = 0; i < 8; ++i) {
        int n = tid * 8 + i;
        int d = 0;
        #pragma unroll
        for (int r = 0; r < RR; ++r)
            d += counts[base + (size_t)r * NN + n];
        invdeg[(size_t)bb * NN + n] = 1.0f / fmaxf((float)d, 1.0f);
    }
}

// ---------------------------------------------------------------------------
// place each edge's src into its bucket slot
// ---------------------------------------------------------------------------
__global__ __launch_bounds__(256) void permute_k(const int* __restrict__ edges,
                                                 const int* __restrict__ types,
                                                 int* __restrict__ cursor,
                                                 int* __restrict__ edgeSrc,
                                                 int b0, int bc)
{
    int t = blockIdx.x * 256 + threadIdx.x;
    int bb = t / EE;
    int e  = t - bb * EE;
    const int* eb = edges + (size_t)(b0 + bb) * 2 * EE;
    int src = eb[e];
    int dst = eb[EE + e];
    int r   = types[(size_t)(b0 + bb) * EE + e];
    int pos = atomicAdd(&cursor[((size_t)bb * RR + r) * NN + dst], 1);
    edgeSrc[(size_t)bb * EE + pos] = src;
}

// ---------------------------------------------------------------------------
// FUSED agg + GEMM, single-buffered A (32 KB), 2 barriers/seg, 3 blocks/CU.
// Block: 64 m-rows x 256 n, 512 threads (8 waves).
// Builder: ONE FULL WAVE PER ROW (wave w owns rows w*8..w*8+7). Lane owns
// cols lane*4..lane*4+3. Per edge: one 8B coalesced load + 4 unpack +
// 2 v_pk_add_f32 — no divergence (all 64 lanes share the row's edge loop).
// Row result packed to 2 uints, one ds_write_b64 into MFMA-frag layout
// (ks-rotated, conflict-free). XCD swizzle keeps each batch's x in one L2.
// ---------------------------------------------------------------------------
template <int WRITE_BF16>
__global__ __launch_bounds__(512, 6) void rgcn_fused(
    const int* __restrict__ offsets, const int* __restrict__ counts,
    const int* __restrict__ edgeSrc, const u16* __restrict__ xin,
    const u16* __restrict__ Wf,      // this layer's frag weights: [9][8][1024][8]
    const float* __restrict__ bias, const float* __restrict__ invdeg,
    float* __restrict__ outF, u16* __restrict__ outH, int relu, int bc)
{
    __shared__ __align__(16) u16 Af[16384];      // 32 KB single buffer
    __shared__ float sInv[TM];
    __shared__ int sStart[8 * TM], sCnt[8 * TM];

    int t = threadIdx.x;
    int fl = t & 63;
    int lane = fl;
    int wid = t >> 6;            // wave id = n-tile (32 cols each) AND row group
    int bid = blockIdx.x;
    int bb, mt0;
    if (bc == 16) {              // XCD swizzle
        bb  = (bid & 7) * 2 + ((bid >> 3) & 1);
        mt0 = bid >> 4;
    } else {
        bb  = bid >> 5;
        mt0 = bid & 31;
    }
    int m0 = mt0 * TM;

    // preload bucket meta: exactly one bucket per thread (8 rel x 64 rows)
    {
        int r = t >> 6, row = t & 63;
        int g = ((bb * RR + r) * NN) + m0 + row;
        sStart[t] = offsets[g];
        sCnt[t]   = counts[g];
    }
    if (t < TM) sInv[t] = invdeg[(size_t)bb * NN + m0 + t];

    const u16* xb = xin + (size_t)bb * NN * DD;
    const int* es = edgeSrc + (size_t)bb * EE;

    // builder lane coords: lane owns k = lane*4..+3
    int ksA_w = lane >> 2;                 // k-octet-pair index 0..15
    int lh_w  = (lane >> 1) & 1;           // which 8-k half
    int half_w = lane & 1;                 // which uint2-half of the octet
    int lh = fl >> 5;                      // acc row mapping

    fx16 acc[2];
    #pragma unroll
    for (int mt = 0; mt < 2; ++mt)
        #pragma unroll
        for (int e = 0; e < 16; ++e) acc[mt][e] = 0.0f;

    __syncthreads();             // meta visible

    for (int seg = 0; seg < 9; ++seg) {
        // ---- build A-tile: 8 rows per wave, full wave per row ----
        #pragma unroll 2
        for (int rr = 0; rr < 8; ++rr) {
            int row = wid * 8 + rr;
            unsigned w0, w1;
            if (seg < 8) {
                f32x2 a01 = {0.f, 0.f}, a23 = {0.f, 0.f};
                int start = sStart[seg * TM + row];
                int cnt   = sCnt[seg * TM + row];
                const int* ep = es + start;
                int j = 0;
                for (; j + 2 <= cnt; j += 2) {
                    int s0 = ep[j], s1 = ep[j + 1];
                    uint2 p = *(const uint2*)(xb + (size_t)s0 * DD + lane * 4);
                    uint2 q = *(const uint2*)(xb + (size_t)s1 * DD + lane * 4);
                    f32x2 p01 = {blo(p.x), bhi(p.x)}, p23 = {blo(p.y), bhi(p.y)};
                    f32x2 q01 = {blo(q.x), bhi(q.x)}, q23 = {blo(q.y), bhi(q.y)};
                    a01 += p01; a23 += p23;
                    a01 += q01; a23 += q23;
                }
                if (j < cnt) {
                    uint2 p = *(const uint2*)(xb + (size_t)ep[j] * DD + lane * 4);
                    f32x2 p01 = {blo(p.x), bhi(p.x)}, p23 = {blo(p.y), bhi(p.y)};
                    a01 += p01; a23 += p23;
                }
                w0 = pk2(a01.x, a01.y);
                w1 = pk2(a23.x, a23.y);
            } else {
                // root segment: direct bf16 copy of x row
                uint2 p = *(const uint2*)(xb + (size_t)(m0 + row) * DD + lane * 4);
                w0 = p.x; w1 = p.y;
            }
            int mt = row >> 5, m31 = row & 31;
            int flw = m31 + 32 * lh_w;
            int off = ((mt * 16 + ksA_w) * 64 + ((flw + ksA_w) & 63)) * 8 + half_w * 4;
            *(uint2*)&Af[off] = make_uint2(w0, w1);
        }
        __syncthreads();         // A ready

        if (seg == 8) {
            // normalize aggregation by degree before the root term
            #pragma unroll
            for (int mt = 0; mt < 2; ++mt)
                #pragma unroll
                for (int r = 0; r < 16; ++r) {
                    int rl = mt * 32 + (r & 3) + 8 * (r >> 2) + 4 * lh;
                    acc[mt][r] *= sInv[rl];
                }
        }

        const u16* Wseg = Wf + (size_t)seg * 65536;
        #pragma unroll 2
        for (int kt = 0; kt < 8; ++kt) {
            bfx8 bfr[2], af[2][2];
            #pragma unroll
            for (int ks2 = 0; ks2 < 2; ++ks2) {
                int ksA = kt * 2 + ks2;
                bfr[ks2] = *(const bfx8*)(Wseg + (size_t)kt * 8192 + wid * 1024
                                          + ks2 * 512 + fl * 8);
                af[0][ks2] = *(const bfx8*)&Af[((0  + ksA) * 64 + ((fl + ksA) & 63)) * 8];
                af[1][ks2] = *(const bfx8*)&Af[((16 + ksA) * 64 + ((fl + ksA) & 63)) * 8];
            }
            #pragma unroll
            for (int ks2 = 0; ks2 < 2; ++ks2) {
                acc[0] = __builtin_amdgcn_mfma_f32_32x32x16_bf16(af[0][ks2], bfr[ks2], acc[0], 0, 0, 0);
                acc[1] = __builtin_amdgcn_mfma_f32_32x32x16_bf16(af[1][ks2], bfr[ks2], acc[1], 0, 0, 0);
            }
        }
        __syncthreads();         // readers done before next build overwrites A
    }

    // ---- epilogue ----
    int col = wid * 32 + (fl & 31);
    float bv = bias[col];
    #pragma unroll
    for (int mt = 0; mt < 2; ++mt)
        #pragma unroll
        for (int r = 0; r < 16; ++r) {
            int row = m0 + mt * 32 + (r & 3) + 8 * (r >> 2) + 4 * lh;
            float v = acc[mt][r] + bv;
            if (relu) v = fmaxf(v, 0.0f);
            if (WRITE_BF16)
                outH[((size_t)bb * NN + row) * DD + col] = f2bf(v);
            else
                outF[((size_t)bb * NN + row) * DD + col] = v;
        }
}

// ---------------------------------------------------------------------------
extern "C" void kernel_launch(void* const* d_in, const int* in_sizes, int n_in,
                              void* d_out, int out_size, void* d_ws, size_t ws_size,
                              hipStream_t stream)
{
    const int*   nodes = (const int*)d_in[0];
    const int*   edges = (const int*)d_in[1];
    const int*   types = (const int*)d_in[2];
    const float* emb   = (const float*)d_in[3];
    const float* W     = (const float*)d_in[4];
    const float* Wroot = (const float*)d_in[5];
    const float* bias  = (const float*)d_in[6];
    float* out = (float*)d_out;

    const size_t wfElems = (size_t)LL * 9 * 8 * 1024 * 8;
    const size_t fixedBytes = wfElems * sizeof(u16);
    const size_t perBatchBytes =
        2 * (size_t)NN * DD * sizeof(u16) + (size_t)NN * sizeof(float) +
        (3 * (size_t)BUCKETS + EE) * sizeof(int);
    int BC = (int)((ws_size - fixedBytes) / perBatchBytes);
    if (BC > BB) BC = BB;
    if (BC < 1) BC = 1;

    u16* Wf      = (u16*)d_ws;
    u16* x0      = Wf + wfElems;
    u16* x1      = x0 + (size_t)BC * NN * DD;
    float* invdeg = (float*)(x1 + (size_t)BC * NN * DD);
    int* counts  = (int*)(invdeg + (size_t)BC * NN);
    int* offsets = counts + (size_t)BC * BUCKETS;
    int* cursor  = offsets + (size_t)BC * BUCKETS;
    int* edgeSrc = cursor + (size_t)BC * BUCKETS;

    for (int b0 = 0; b0 < BB; b0 += BC) {
        int bc = BB - b0 < BC ? BB - b0 : BC;

        int zeroBlocks = (bc * BUCKETS / 4 + 255) / 256;
        prep0<<<8 * LL * 9 + zeroBlocks, 256, 0, stream>>>(W, Wroot, Wf, counts, bc);
        prep1<<<bc * 640, 256, 0, stream>>>(nodes, emb, x0, edges, types, counts, b0, bc);
        scan2_k<<<bc, 256, 0, stream>>>(counts, offsets, cursor, invdeg);
        permute_k<<<bc * 128, 256, 0, stream>>>(edges, types, cursor, edgeSrc, b0, bc);

        for (int l = 0; l < LL; ++l) {
            const u16* xin = (l == 0) ? x0 : x1;
            const u16* Wfl = Wf + (size_t)l * 9 * 65536;
            if (l == 0)
                rgcn_fused<1><<<bc * 32, 512, 0, stream>>>(offsets, counts, edgeSrc,
                    xin, Wfl, bias + (size_t)l * DD, invdeg, nullptr, x1, 1, bc);
            else
                rgcn_fused<0><<<bc * 32, 512, 0, stream>>>(offsets, counts, edgeSrc,
                    xin, Wfl, bias + (size_t)l * DD, invdeg,
                    out + (size_t)b0 * NN * DD, nullptr, 0, bc);
        }
    }
}